// Round 4
// baseline (606.303 us; speedup 1.0000x reference)
//
#include <hip/hip_runtime.h>

// Problem constants
#define CV   34          // C*V channels
#define TTOT 2048        // T
#define NB   512         // batches
#define XB   69632       // x per-batch stride (2*2048*17)
#define XC   34816       // x per-co stride (2048*17)

// Workspace layout (floats)
#define GS_STRIDE 1192                   // per-batch: G (1156) + s0 (34) + pad
#define RB_OFF    (512 * 1192)           // region B offset
// region B per batch: 1024 ushort (hi/lo bf16 planes, 16x32) = 512 f,
// then cy[16], wy32[16], wy33[16] f32 -> 560 f, padded to 576
#define RB_STRIDE 576

typedef __attribute__((ext_vector_type(8))) short v8s;   // 8 x bf16 (MFMA A/B frag)
typedef __attribute__((ext_vector_type(4))) float v4f;   // 4 x f32 (MFMA C/D frag)

__device__ __forceinline__ unsigned short f2bf(float f) {
    unsigned int u = __float_as_uint(f);
    u = u + 0x7FFFu + ((u >> 16) & 1u);   // round-to-nearest-even
    return (unsigned short)(u >> 16);
}
__device__ __forceinline__ float bf2f(unsigned short s) {
    return __uint_as_float(((unsigned int)s) << 16);
}

__device__ __forceinline__ unsigned int cvtpk_bf16(float a, float b) {
    unsigned int r;   // r.lo16 = bf16(a), r.hi16 = bf16(b), RNE
    asm("v_cvt_pk_bf16_f32 %0, %1, %2" : "=v"(r) : "v"(a), "v"(b));
    return r;
}

// split 8 f32 -> packed hi/lo bf16 MFMA fragments (RNE; residual exact in f32)
__device__ __forceinline__ void split8(const float (&f)[8], v8s* hi, v8s* lo) {
    union { unsigned int u[4]; v8s s; } H, L;
#pragma unroll
    for (int p = 0; p < 4; ++p) {
        float a = f[2 * p], b = f[2 * p + 1];
        unsigned int h = cvtpk_bf16(a, b);
        float ra = a - __uint_as_float(h << 16);
        float rb = b - __uint_as_float(h & 0xFFFF0000u);
        L.u[p] = cvtpk_bf16(ra, rb);
        H.u[p] = h;
    }
    *hi = H.s;
    *lo = L.s;
}

// async-stage one 128-t chunk (2 co x 2176 floats, verbatim global order) to LDS.
// 17 x global_load_lds(16B); wave w issues instrs {w, w+4, ...}.
__device__ __forceinline__ void stage_chunk(const float* __restrict__ xb, int t0,
                                            float* rawbuf, int w, int lane) {
#pragma unroll
    for (int i = 0; i < 5; ++i) {
        int idx = i * 4 + w;
        if (idx < 17) {
            int fl = idx * 256 + lane * 4;
            int co = (fl >= 2176) ? 1 : 0;
            const float* g = xb + t0 * 17 + fl + co * 32640;   // 32640 = XC - 2176
            __builtin_amdgcn_global_load_lds(
                (const __attribute__((address_space(1))) void*)g,
                (__attribute__((address_space(3))) void*)(rawbuf + idx * 256),
                16, 0, 0);
        }
    }
}

// ---------------------------------------------------------------------------
// K1: per-(batch, t-segment) partial Gram G += Hseg Hseg^T (34x34) and s0.
// Async f32 staging (double-buffered) + in-register hi/lo split at frag build.
// ---------------------------------------------------------------------------
struct SmemGramB {
    float Gpart[4][34][36];
    float spart[4][36];
};

__global__ __launch_bounds__(256, 4) void k_gram(const float* __restrict__ x,
                                                 float* __restrict__ ws) {
    __shared__ __align__(16) union {
        float raw[2][4352];      // 2 x (2 co x 2176 f32)  = 34,816 B
        SmemGramB b;             // epilogue reduction area = 20,160 B
    } sm;

    const int b    = blockIdx.x >> 2;
    const int seg  = blockIdx.x & 3;          // 4 segments of 512 t
    const int tid  = threadIdx.x;
    const int l    = tid & 63;
    const int w    = tid >> 6;                // wave id 0..3 -> k-slice in chunk
    const int row16 = l & 15;
    const int quad  = l >> 4;
    const float* xb = x + (size_t)b * XB;
    const int t0 = seg * 512;

    // per-lane dword offsets for channel c = r*16+row16 (clamped: rows 34..47
    // duplicate row 33; their MFMA outputs land in discarded C rows/cols)
    int offc[3];
#pragma unroll
    for (int r = 0; r < 3; ++r) {
        int c = r * 16 + row16;
        if (c > 33) c = 33;
        offc[r] = (c >= 17) ? (2159 + c) : c;   // = co*2176 + v
    }
    const int koff = w * 32 + quad * 8;        // t offset within 128-t chunk

    v4f accG[3][3];
    v4f accS[3];
    v4f vz = {0.f, 0.f, 0.f, 0.f};
#pragma unroll
    for (int r = 0; r < 3; ++r) {
        accS[r] = vz;
#pragma unroll
        for (int c = 0; c < 3; ++c) accG[r][c] = vz;
    }
    v8s ones;
#pragma unroll
    for (int i = 0; i < 8; ++i) ones[i] = (short)0x3F80;   // bf16 1.0

    stage_chunk(xb, t0, sm.raw[0], w, l);
    __syncthreads();                           // drains vmcnt(0): chunk 0 ready

    for (int ch = 0; ch < 4; ++ch) {           // 4 chunks of 128 t
        const int cur = ch & 1;
        if (ch < 3) stage_chunk(xb, t0 + (ch + 1) * 128, sm.raw[cur ^ 1], w, l);

        const float* rb = sm.raw[cur] + koff * 17;
        v8s fh[3], fl4[3];
#pragma unroll
        for (int r = 0; r < 3; ++r) {
            const float* p = rb + offc[r];
            float f[8];
#pragma unroll
            for (int e = 0; e < 8; ++e) f[e] = p[e * 17];   // 8 x ds_read_b32, imm offs
            split8(f, &fh[r], &fl4[r]);
        }
#pragma unroll
        for (int r = 0; r < 3; ++r) {
#pragma unroll
            for (int c = 0; c < 3; ++c) {
                accG[r][c] = __builtin_amdgcn_mfma_f32_16x16x32_bf16(fh[r],  fh[c],  accG[r][c], 0, 0, 0);
                accG[r][c] = __builtin_amdgcn_mfma_f32_16x16x32_bf16(fh[r],  fl4[c], accG[r][c], 0, 0, 0);
                accG[r][c] = __builtin_amdgcn_mfma_f32_16x16x32_bf16(fl4[r], fh[c],  accG[r][c], 0, 0, 0);
            }
            accS[r] = __builtin_amdgcn_mfma_f32_16x16x32_bf16(fh[r],  ones, accS[r], 0, 0, 0);
            accS[r] = __builtin_amdgcn_mfma_f32_16x16x32_bf16(fl4[r], ones, accS[r], 0, 0, 0);
        }
        __syncthreads();   // drains next-chunk stage; protects buffer reuse
    }

    // epilogue: union switched to sm.b (all raw reads complete + barrier passed)
#pragma unroll
    for (int r = 0; r < 3; ++r) {
#pragma unroll
        for (int c = 0; c < 3; ++c) {
#pragma unroll
            for (int i = 0; i < 4; ++i) {
                int m = r * 16 + quad * 4 + i;
                int n = c * 16 + row16;
                if (m < 34 && n < 34) sm.b.Gpart[w][m][n] = accG[r][c][i];
            }
        }
        if (row16 == 0) {
#pragma unroll
            for (int i = 0; i < 4; ++i) {
                int m = r * 16 + quad * 4 + i;
                if (m < 34) sm.b.spart[w][m] = accS[r][i];
            }
        }
    }
    __syncthreads();
    float* gout = ws + (size_t)b * GS_STRIDE;
    for (int idx = tid; idx < 1156; idx += 256) {
        int m = idx / 34, n = idx - m * 34;
        atomicAdd(&gout[idx], sm.b.Gpart[0][m][n] + sm.b.Gpart[1][m][n] +
                              sm.b.Gpart[2][m][n] + sm.b.Gpart[3][m][n]);
    }
    if (tid < 34)
        atomicAdd(&gout[1156 + tid], sm.b.spart[0][tid] + sm.b.spart[1][tid] +
                                     sm.b.spart[2][tid] + sm.b.spart[3][tid]);
}

// ---------------------------------------------------------------------------
// K2: per-batch affine chain, wave-synchronous, TWO BATCHES PER WAVE for ILP
// (single wave per SIMD cannot hide latency across waves; interleaving two
// independent chains in one issue stream fills the stalls). Augmented-matrix
// algebra: offsets ride row/col 34; G0 augmented with s0 / T. Fully inlined
// and unrolled (round-2 codegen); W global loads shared between the banks.
// LDS: 6 arrays x 1296 f per bank (Sc aliases dead Aq) = 62,208 B static.
// ---------------------------------------------------------------------------
#define BANKF   7776
#define OFF_G0  0
#define OFF_At  1296
#define OFF_AqSc 2592
#define OFF_Ak  3888
#define OFF_AvT 5184
#define OFF_S1  6480

// Dual-bank D = L * R^T over e<36 (pads zero). Lane tile: 9 rows x cols
// {lc, lc+16, lc+32 (lc<3)}. L-reads broadcast per 16-lane group.
__device__ __forceinline__ void wave_mm2(const float* __restrict__ LA,
                                         const float* __restrict__ RA,
                                         float* __restrict__ DA,
                                         const float* __restrict__ LB,
                                         const float* __restrict__ RB,
                                         float* __restrict__ DB, int l) {
    const int lr = l >> 4, lc = l & 15;
    const int i0 = lr * 9;
    const bool has3 = (lc < 3);
    const int r2 = has3 ? (lc + 32) : 0;
    float a0A[9], a1A[9], a2A[9], a0B[9], a1B[9], a2B[9];
#pragma unroll
    for (int a = 0; a < 9; ++a) {
        a0A[a] = 0.f; a1A[a] = 0.f; a2A[a] = 0.f;
        a0B[a] = 0.f; a1B[a] = 0.f; a2B[a] = 0.f;
    }
#pragma unroll
    for (int e0 = 0; e0 < 36; e0 += 4) {
        const float4 r0A = *(const float4*)(RA + lc * 36 + e0);
        const float4 r1A = *(const float4*)(RA + (lc + 16) * 36 + e0);
        const float4 r2A = *(const float4*)(RA + r2 * 36 + e0);
        const float4 r0B = *(const float4*)(RB + lc * 36 + e0);
        const float4 r1B = *(const float4*)(RB + (lc + 16) * 36 + e0);
        const float4 r2B = *(const float4*)(RB + r2 * 36 + e0);
#pragma unroll
        for (int a = 0; a < 9; ++a) {
            const float4 lA = *(const float4*)(LA + (i0 + a) * 36 + e0);
            const float4 lB = *(const float4*)(LB + (i0 + a) * 36 + e0);
            a0A[a] += lA.x * r0A.x + lA.y * r0A.y + lA.z * r0A.z + lA.w * r0A.w;
            a1A[a] += lA.x * r1A.x + lA.y * r1A.y + lA.z * r1A.z + lA.w * r1A.w;
            a2A[a] += lA.x * r2A.x + lA.y * r2A.y + lA.z * r2A.z + lA.w * r2A.w;
            a0B[a] += lB.x * r0B.x + lB.y * r0B.y + lB.z * r0B.z + lB.w * r0B.w;
            a1B[a] += lB.x * r1B.x + lB.y * r1B.y + lB.z * r1B.z + lB.w * r1B.w;
            a2B[a] += lB.x * r2B.x + lB.y * r2B.y + lB.z * r2B.z + lB.w * r2B.w;
        }
    }
#pragma unroll
    for (int a = 0; a < 9; ++a) {
        DA[(i0 + a) * 36 + lc]      = a0A[a];
        DA[(i0 + a) * 36 + lc + 16] = a1A[a];
        DB[(i0 + a) * 36 + lc]      = a0B[a];
        DB[(i0 + a) * 36 + lc + 16] = a1B[a];
        if (has3) {
            DA[(i0 + a) * 36 + lc + 32] = a2A[a];
            DB[(i0 + a) * 36 + lc + 32] = a2B[a];
        }
    }
}

// Dual-bank D = W * R^T, W global (nrows x 34 row-major), e<34; rows >= nrows
// give zero. W loads are SHARED between banks. transpose=1 writes D[j][i].
__device__ __forceinline__ void wave_mmG2(const float* __restrict__ Wg, int nrows,
                                          const float* __restrict__ RA,
                                          float* __restrict__ DA,
                                          const float* __restrict__ RB,
                                          float* __restrict__ DB,
                                          int transpose, int l) {
    const int lr = l >> 4, lc = l & 15;
    const int i0 = lr * 9;
    const bool has3 = (lc < 3);
    const int r2 = has3 ? (lc + 32) : 0;
    float a0A[9], a1A[9], a2A[9], a0B[9], a1B[9], a2B[9];
#pragma unroll
    for (int a = 0; a < 9; ++a) {
        a0A[a] = 0.f; a1A[a] = 0.f; a2A[a] = 0.f;
        a0B[a] = 0.f; a1B[a] = 0.f; a2B[a] = 0.f;
    }
#pragma unroll
    for (int e0 = 0; e0 < 32; e0 += 4) {
        const float4 r0A = *(const float4*)(RA + lc * 36 + e0);
        const float4 r1A = *(const float4*)(RA + (lc + 16) * 36 + e0);
        const float4 r2A = *(const float4*)(RA + r2 * 36 + e0);
        const float4 r0B = *(const float4*)(RB + lc * 36 + e0);
        const float4 r1B = *(const float4*)(RB + (lc + 16) * 36 + e0);
        const float4 r2B = *(const float4*)(RB + r2 * 36 + e0);
#pragma unroll
        for (int a = 0; a < 9; ++a) {
            const int i = i0 + a;
            float2 la = make_float2(0.f, 0.f), lb = make_float2(0.f, 0.f);
            if (i < nrows) {
                la = *(const float2*)(Wg + i * 34 + e0);
                lb = *(const float2*)(Wg + i * 34 + e0 + 2);
            }
            a0A[a] += la.x * r0A.x + la.y * r0A.y + lb.x * r0A.z + lb.y * r0A.w;
            a1A[a] += la.x * r1A.x + la.y * r1A.y + lb.x * r1A.z + lb.y * r1A.w;
            a2A[a] += la.x * r2A.x + la.y * r2A.y + lb.x * r2A.z + lb.y * r2A.w;
            a0B[a] += la.x * r0B.x + la.y * r0B.y + lb.x * r0B.z + lb.y * r0B.w;
            a1B[a] += la.x * r1B.x + la.y * r1B.y + lb.x * r1B.z + lb.y * r1B.w;
            a2B[a] += la.x * r2B.x + la.y * r2B.y + lb.x * r2B.z + lb.y * r2B.w;
        }
    }
    {   // tail e = 32, 33
        const float q0A = RA[lc * 36 + 32],        q1A = RA[lc * 36 + 33];
        const float q2A = RA[(lc + 16) * 36 + 32], q3A = RA[(lc + 16) * 36 + 33];
        const float q4A = RA[r2 * 36 + 32],        q5A = RA[r2 * 36 + 33];
        const float q0B = RB[lc * 36 + 32],        q1B = RB[lc * 36 + 33];
        const float q2B = RB[(lc + 16) * 36 + 32], q3B = RB[(lc + 16) * 36 + 33];
        const float q4B = RB[r2 * 36 + 32],        q5B = RB[r2 * 36 + 33];
#pragma unroll
        for (int a = 0; a < 9; ++a) {
            const int i = i0 + a;
            float2 la = make_float2(0.f, 0.f);
            if (i < nrows) la = *(const float2*)(Wg + i * 34 + 32);
            a0A[a] += la.x * q0A + la.y * q1A;
            a1A[a] += la.x * q2A + la.y * q3A;
            a2A[a] += la.x * q4A + la.y * q5A;
            a0B[a] += la.x * q0B + la.y * q1B;
            a1B[a] += la.x * q2B + la.y * q3B;
            a2B[a] += la.x * q4B + la.y * q5B;
        }
    }
#pragma unroll
    for (int a = 0; a < 9; ++a) {
        const int i = i0 + a;
        if (transpose) {
            DA[lc * 36 + i]        = a0A[a];
            DA[(lc + 16) * 36 + i] = a1A[a];
            DB[lc * 36 + i]        = a0B[a];
            DB[(lc + 16) * 36 + i] = a1B[a];
            if (has3) {
                DA[(lc + 32) * 36 + i] = a2A[a];
                DB[(lc + 32) * 36 + i] = a2B[a];
            }
        } else {
            DA[i * 36 + lc]      = a0A[a];
            DA[i * 36 + lc + 16] = a1A[a];
            DB[i * 36 + lc]      = a0B[a];
            DB[i * 36 + lc + 16] = a1B[a];
            if (has3) {
                DA[i * 36 + lc + 32] = a2A[a];
                DB[i * 36 + lc + 32] = a2B[a];
            }
        }
    }
}

__global__ __launch_bounds__(64, 1) void k_chain(
    const float* __restrict__ wq, const float* __restrict__ bq,
    const float* __restrict__ wk, const float* __restrict__ bk,
    const float* __restrict__ wv, const float* __restrict__ bv,
    const float* __restrict__ w1, const float* __restrict__ b1,
    const float* __restrict__ gamma, const float* __restrict__ beta,
    const float* __restrict__ mean, const float* __restrict__ var,
    float* __restrict__ ws) {
    __shared__ float SM[2 * BANKF];
    const int l = threadIdx.x;
    const int b0 = blockIdx.x * 2;
    const float* gsb0 = ws + (size_t)b0 * GS_STRIDE;
    const float* gsb1 = gsb0 + GS_STRIDE;

    float* G0A = SM + OFF_G0;          float* G0B = SM + BANKF + OFF_G0;
    float* AtA = SM + OFF_At;          float* AtB = SM + BANKF + OFF_At;
    float* AqA = SM + OFF_AqSc;        float* AqB = SM + BANKF + OFF_AqSc;
    float* AkA = SM + OFF_Ak;          float* AkB = SM + BANKF + OFF_Ak;
    float* AvA = SM + OFF_AvT;         float* AvB = SM + BANKF + OFF_AvT;
    float* S1A = SM + OFF_S1;          float* S1B = SM + BANKF + OFF_S1;

    // zero all LDS (pads must be 0 and stay 0)
    {
        const float4 z = make_float4(0.f, 0.f, 0.f, 0.f);
        for (int i = l * 4; i < 2 * BANKF; i += 256) *(float4*)(SM + i) = z;
    }
    __syncthreads();
    // load augmented G0 + layer-0 shortcut (A=I, a=0): Aq=wq0(+bq col34),
    // Ak=wk0(+bk col34), AvT=wv0^T(+bv row34)
    for (int idx = l; idx < 1156; idx += 64) {
        int m = idx / 34, n = idx - m * 34;
        G0A[m * 36 + n] = gsb0[idx];
        G0B[m * 36 + n] = gsb1[idx];
        float q = wq[idx], k = wk[idx], v = wv[idx];
        AqA[m * 36 + n] = q;  AqB[m * 36 + n] = q;
        AkA[m * 36 + n] = k;  AkB[m * 36 + n] = k;
        AvA[n * 36 + m] = v;  AvB[n * 36 + m] = v;
    }
    if (l < 34) {
        float sA = gsb0[1156 + l], sB = gsb1[1156 + l];
        G0A[34 * 36 + l] = sA;  G0A[l * 36 + 34] = sA;
        G0B[34 * 36 + l] = sB;  G0B[l * 36 + 34] = sB;
        float vq = bq[l], vk = bk[l], vv = bv[l];
        AqA[l * 36 + 34] = vq;  AqB[l * 36 + 34] = vq;
        AkA[l * 36 + 34] = vk;  AkB[l * 36 + 34] = vk;
        AvA[34 * 36 + l] = vv;  AvB[34 * 36 + l] = vv;
    }
    if (l == 0) { G0A[34 * 36 + 34] = 2048.0f; G0B[34 * 36 + 34] = 2048.0f; }
    __syncthreads();

    for (int lyr = 0; lyr < 3; ++lyr) {
        if (lyr > 0) {
            const float* wql = wq + lyr * 1156;
            const float* wkl = wk + lyr * 1156;
            const float* wvl = wv + lyr * 1156;
            // stage1: Aq^ = Wq*A^, Ak^ = Wk*A^, AvT^ = (Wv*A^)^T
            wave_mmG2(wql, 34, AtA, AqA, AtB, AqB, 0, l);
            wave_mmG2(wkl, 34, AtA, AkA, AtB, AkB, 0, l);
            wave_mmG2(wvl, 34, AtA, AvA, AtB, AvB, 1, l);
            __syncthreads();
            if (l < 34) {     // add biases to the offset slots
                float vq = bq[lyr * 34 + l], vk = bk[lyr * 34 + l], vv = bv[lyr * 34 + l];
                AqA[l * 36 + 34] += vq;  AqB[l * 36 + 34] += vq;
                AkA[l * 36 + 34] += vk;  AkB[l * 36 + 34] += vk;
                AvA[34 * 36 + l] += vv;  AvB[34 * 36 + l] += vv;
            }
            __syncthreads();
        }
        // stage2: S1 = Aq^ * G0^  (G0^ symmetric)
        wave_mm2(AqA, G0A, S1A, AqB, G0B, S1B, l);
        __syncthreads();
        // stage3: Sc = S1 * Ak^T  (exact augmented scores; Sc aliases dead Aq)
        wave_mm2(S1A, AkA, AqA, S1B, AkB, AqB, l);
        __syncthreads();
        // stage4: row softmax, both banks interleaved (rows/cols < 34)
        if (l < 34) {
            float fA[36], fB[36];
#pragma unroll
            for (int e0 = 0; e0 < 36; e0 += 4) {
                *(float4*)&fA[e0] = *(const float4*)(AqA + l * 36 + e0);
                *(float4*)&fB[e0] = *(const float4*)(AqB + l * 36 + e0);
            }
            const float scale = 0.022097086912079608f;   // 1/sqrt(2048)
            float mA = -1e30f, mB = -1e30f;
#pragma unroll
            for (int d = 0; d < 34; ++d) {
                fA[d] *= scale; fB[d] *= scale;
                mA = fmaxf(mA, fA[d]); mB = fmaxf(mB, fB[d]);
            }
            float sA = 0.f, sB = 0.f;
#pragma unroll
            for (int d = 0; d < 34; ++d) {
                float eA = __expf(fA[d] - mA), eB = __expf(fB[d] - mB);
                fA[d] = eA; fB[d] = eB; sA += eA; sB += eB;
            }
            float rA = 1.0f / sA, rB = 1.0f / sB;
#pragma unroll
            for (int d = 0; d < 34; ++d) { fA[d] *= rA; fB[d] *= rB; }
            fA[34] = 0.f; fA[35] = 0.f; fB[34] = 0.f; fB[35] = 0.f;
#pragma unroll
            for (int e0 = 0; e0 < 36; e0 += 4) {
                *(float4*)(AqA + l * 36 + e0) = *(const float4*)&fA[e0];
                *(float4*)(AqB + l * 36 + e0) = *(const float4*)&fB[e0];
            }
        }
        __syncthreads();
        // stage5: At' = AvT^ * attn^T; row 34 auto-propagates offset a'
        wave_mm2(AvA, AqA, AtA, AvB, AqB, AtB, l);
        __syncthreads();
    }

    // head: S1[o][j] = (w1 * A3^)[o][j]; col 34 = W1*a (= cy_raw - b1)
    wave_mmG2(w1, 16, AtA, S1A, AtB, S1B, 0, l);
    __syncthreads();
    // emit compact Wy' for both banks: bf16 hi/lo (c<32), f32 cols 32/33, cy
#pragma unroll
    for (int bk = 0; bk < 2; ++bk) {
        const float* S1p = (bk == 0) ? S1A : S1B;
        float* wb = ws + RB_OFF + (size_t)(b0 + bk) * RB_STRIDE;
        if (l < 16) {
            float iv = gamma[l] * rsqrtf(var[l] + 1e-5f);
            float cyraw = S1p[l * 36 + 34] + b1[l];
            wb[512 + l] = (cyraw - mean[l]) * iv + beta[l];   // cy'
            wb[528 + l] = S1p[l * 36 + 32] * iv;              // wy32
            wb[544 + l] = S1p[l * 36 + 33] * iv;              // wy33
        }
        unsigned short* wp = (unsigned short*)wb;
        for (int i = l; i < 512; i += 64) {
            int o = i >> 5, c = i & 31;
            float iv = gamma[o] * rsqrtf(var[o] + 1e-5f);
            float vv = S1p[o * 36 + c] * iv;
            unsigned short hb = f2bf(vv);
            wp[i] = hb;
            wp[512 + i] = f2bf(vv - bf2f(hb));
        }
    }
}

// ---------------------------------------------------------------------------
// K3: out = w2 * leaky(Wy' h0 + cy') + b2. Async f32 staging + in-register
// split at B-frag build; channels 32/33 via exact f32 scalar FMA (MFMA halved).
// ---------------------------------------------------------------------------
__global__ __launch_bounds__(256, 4) void k_out(const float* __restrict__ x,
                                                const float* __restrict__ w2,
                                                const float* __restrict__ b2,
                                                const float* __restrict__ ws,
                                                float* __restrict__ out) {
    __shared__ __align__(16) float raw[2][4352];

    const int tid  = threadIdx.x;
    const int b    = blockIdx.x >> 3;
    const int seg  = (blockIdx.x & 7) * 256;
    const int l    = tid & 63;
    const int w    = tid >> 6;
    const int quad = l >> 4;
    const int col  = l & 15;

    const float* wb = ws + RB_OFF + (size_t)b * RB_STRIDE;
    const unsigned short* wp = (const unsigned short*)wb;
    v8s aH = *(const v8s*)&wp[col * 32 + quad * 8];
    v8s aL = *(const v8s*)&wp[512 + col * 32 + quad * 8];
    float cyr[4], w2r[3][4], wy32r[4], wy33r[4];
#pragma unroll
    for (int i = 0; i < 4; ++i) {
        int o = quad * 4 + i;
        cyr[i]   = wb[512 + o];
        wy32r[i] = wb[528 + o];
        wy33r[i] = wb[544 + o];
#pragma unroll
        for (int p = 0; p < 3; ++p) w2r[p][i] = w2[p * 16 + o];
    }
    float b2r[3] = {b2[0], b2[1], b2[2]};
    const float* xb = x + (size_t)b * XB;

    // per-lane dword offsets for channels c = quad*8+e (all real, c < 32)
    int offq[8];
#pragma unroll
    for (int e = 0; e < 8; ++e) {
        int c = quad * 8 + e;
        offq[e] = (c >= 17) ? (2159 + c) : c;   // = co*2176 + v
    }

    stage_chunk(xb, seg, raw[0], w, l);
    __syncthreads();

    for (int ch = 0; ch < 2; ++ch) {
        if (ch == 0) stage_chunk(xb, seg + 128, raw[1], w, l);
        for (int tt = w; tt < 8; tt += 4) {
            const int tl = tt * 16 + col;
            const float* rbt = raw[ch] + tl * 17;
            float f[8];
#pragma unroll
            for (int e = 0; e < 8; ++e) f[e] = rbt[offq[e]];
            v8s bH, bL;
            split8(f, &bH, &bL);
            v4f acc = {0.f, 0.f, 0.f, 0.f};
            acc = __builtin_amdgcn_mfma_f32_16x16x32_bf16(aH, bH, acc, 0, 0, 0);
            acc = __builtin_amdgcn_mfma_f32_16x16x32_bf16(aH, bL, acc, 0, 0, 0);
            acc = __builtin_amdgcn_mfma_f32_16x16x32_bf16(aL, bH, acc, 0, 0, 0);
            float h32 = rbt[2191];   // c=32 (co1, v15) — LDS broadcast across quads
            float h33 = rbt[2192];   // c=33 (co1, v16)
            float op[3] = {0, 0, 0};
#pragma unroll
            for (int i = 0; i < 4; ++i) {
                float y = acc[i] + cyr[i] + wy32r[i] * h32 + wy33r[i] * h33;
                float z = (y > 0.f) ? y : 0.01f * y;
#pragma unroll
                for (int p = 0; p < 3; ++p) op[p] += w2r[p][i] * z;
            }
#pragma unroll
            for (int p = 0; p < 3; ++p) {
                op[p] += __shfl_xor(op[p], 16);
                op[p] += __shfl_xor(op[p], 32);
            }
            if (l < 16) {
                int tg = seg + ch * 128 + tt * 16 + l;
#pragma unroll
                for (int p = 0; p < 3; ++p)
                    out[((size_t)b * 3 + p) * 2048 + tg] = op[p] + b2r[p];
            }
        }
        __syncthreads();   // drains chunk-1 stage; protects buffer before exit
    }
}

extern "C" void kernel_launch(void* const* d_in, const int* in_sizes, int n_in,
                              void* d_out, int out_size, void* d_ws, size_t ws_size,
                              hipStream_t stream) {
    const float* x     = (const float*)d_in[0];
    const float* wq    = (const float*)d_in[1];
    const float* bq    = (const float*)d_in[2];
    const float* wk    = (const float*)d_in[3];
    const float* bk    = (const float*)d_in[4];
    const float* wv    = (const float*)d_in[5];
    const float* bv    = (const float*)d_in[6];
    const float* w1    = (const float*)d_in[7];
    const float* b1    = (const float*)d_in[8];
    const float* gamma = (const float*)d_in[9];
    const float* beta  = (const float*)d_in[10];
    const float* mean  = (const float*)d_in[11];
    const float* var   = (const float*)d_in[12];
    const float* w2    = (const float*)d_in[13];
    const float* b2    = (const float*)d_in[14];
    float* ws  = (float*)d_ws;
    float* out = (float*)d_out;

    hipMemsetAsync(d_ws, 0, (size_t)NB * GS_STRIDE * sizeof(float), stream);
    k_gram<<<dim3(2048), dim3(256), 0, stream>>>(x, ws);
    k_chain<<<dim3(256), dim3(64), 0, stream>>>(wq, bq, wk, bk, wv, bv,
                                                w1, b1, gamma, beta, mean, var, ws);
    k_out<<<dim3(4096), dim3(256), 0, stream>>>(x, w2, b2, ws, out);
}

// Round 5
// 316.591 us; speedup vs baseline: 1.9151x; 1.9151x over previous
//
#include <hip/hip_runtime.h>

// Problem constants
#define CV   34          // C*V channels
#define TTOT 2048        // T
#define NB   512         // batches
#define XB   69632       // x per-batch stride (2*2048*17)
#define XC   34816       // x per-co stride (2048*17)

// Workspace layout (floats)
#define GS_STRIDE 1192                   // per-batch: G (1156) + s0 (34) + pad
#define RB_OFF    (512 * 1192)           // region B offset
// region B per batch: 1024 ushort (hi/lo bf16 planes, 16x32) = 512 f,
// then cy[16], wy32[16], wy33[16] f32 -> 560 f, padded to 576
#define RB_STRIDE 576

typedef __attribute__((ext_vector_type(8))) short v8s;   // 8 x bf16 (MFMA A/B frag)
typedef __attribute__((ext_vector_type(4))) float v4f;   // 4 x f32 (MFMA C/D frag)

__device__ __forceinline__ unsigned short f2bf(float f) {
    unsigned int u = __float_as_uint(f);
    u = u + 0x7FFFu + ((u >> 16) & 1u);   // round-to-nearest-even
    return (unsigned short)(u >> 16);
}
__device__ __forceinline__ float bf2f(unsigned short s) {
    return __uint_as_float(((unsigned int)s) << 16);
}

__device__ __forceinline__ unsigned int cvtpk_bf16(float a, float b) {
    unsigned int r;   // r.lo16 = bf16(a), r.hi16 = bf16(b), RNE
    asm("v_cvt_pk_bf16_f32 %0, %1, %2" : "=v"(r) : "v"(a), "v"(b));
    return r;
}

// split 8 f32 -> packed hi/lo bf16 MFMA fragments (RNE; residual exact in f32)
__device__ __forceinline__ void split8(const float (&f)[8], v8s* hi, v8s* lo) {
    union { unsigned int u[4]; v8s s; } H, L;
#pragma unroll
    for (int p = 0; p < 4; ++p) {
        float a = f[2 * p], b = f[2 * p + 1];
        unsigned int h = cvtpk_bf16(a, b);
        float ra = a - __uint_as_float(h << 16);
        float rb = b - __uint_as_float(h & 0xFFFF0000u);
        L.u[p] = cvtpk_bf16(ra, rb);
        H.u[p] = h;
    }
    *hi = H.s;
    *lo = L.s;
}

// async-stage one 128-t chunk (2 co x 2176 floats, verbatim global order) to LDS.
// 17 x global_load_lds(16B); wave w issues instrs {w, w+4, ...}.
__device__ __forceinline__ void stage_chunk(const float* __restrict__ xb, int t0,
                                            float* rawbuf, int w, int lane) {
#pragma unroll
    for (int i = 0; i < 5; ++i) {
        int idx = i * 4 + w;
        if (idx < 17) {
            int fl = idx * 256 + lane * 4;
            int co = (fl >= 2176) ? 1 : 0;
            const float* g = xb + t0 * 17 + fl + co * 32640;   // 32640 = XC - 2176
            __builtin_amdgcn_global_load_lds(
                (const __attribute__((address_space(1))) void*)g,
                (__attribute__((address_space(3))) void*)(rawbuf + idx * 256),
                16, 0, 0);
        }
    }
}

// ---------------------------------------------------------------------------
// K1: per-(batch, t-segment) partial Gram G += Hseg Hseg^T (34x34) and s0.
// ---------------------------------------------------------------------------
struct SmemGramB {
    float Gpart[4][34][36];
    float spart[4][36];
};

__global__ __launch_bounds__(256, 4) void k_gram(const float* __restrict__ x,
                                                 float* __restrict__ ws) {
    __shared__ __align__(16) union {
        float raw[2][4352];      // 2 x (2 co x 2176 f32)  = 34,816 B
        SmemGramB b;             // epilogue reduction area = 20,160 B
    } sm;

    const int b    = blockIdx.x >> 2;
    const int seg  = blockIdx.x & 3;          // 4 segments of 512 t
    const int tid  = threadIdx.x;
    const int l    = tid & 63;
    const int w    = tid >> 6;                // wave id 0..3 -> k-slice in chunk
    const int row16 = l & 15;
    const int quad  = l >> 4;
    const float* xb = x + (size_t)b * XB;
    const int t0 = seg * 512;

    int offc[3];
#pragma unroll
    for (int r = 0; r < 3; ++r) {
        int c = r * 16 + row16;
        if (c > 33) c = 33;
        offc[r] = (c >= 17) ? (2159 + c) : c;   // = co*2176 + v
    }
    const int koff = w * 32 + quad * 8;        // t offset within 128-t chunk

    v4f accG[3][3];
    v4f accS[3];
    v4f vz = {0.f, 0.f, 0.f, 0.f};
#pragma unroll
    for (int r = 0; r < 3; ++r) {
        accS[r] = vz;
#pragma unroll
        for (int c = 0; c < 3; ++c) accG[r][c] = vz;
    }
    v8s ones;
#pragma unroll
    for (int i = 0; i < 8; ++i) ones[i] = (short)0x3F80;   // bf16 1.0

    stage_chunk(xb, t0, sm.raw[0], w, l);
    __syncthreads();                           // drains vmcnt(0): chunk 0 ready

    for (int ch = 0; ch < 4; ++ch) {           // 4 chunks of 128 t
        const int cur = ch & 1;
        if (ch < 3) stage_chunk(xb, t0 + (ch + 1) * 128, sm.raw[cur ^ 1], w, l);

        const float* rb = sm.raw[cur] + koff * 17;
        v8s fh[3], fl4[3];
#pragma unroll
        for (int r = 0; r < 3; ++r) {
            const float* p = rb + offc[r];
            float f[8];
#pragma unroll
            for (int e = 0; e < 8; ++e) f[e] = p[e * 17];   // 8 x ds_read_b32
            split8(f, &fh[r], &fl4[r]);
        }
#pragma unroll
        for (int r = 0; r < 3; ++r) {
#pragma unroll
            for (int c = 0; c < 3; ++c) {
                accG[r][c] = __builtin_amdgcn_mfma_f32_16x16x32_bf16(fh[r],  fh[c],  accG[r][c], 0, 0, 0);
                accG[r][c] = __builtin_amdgcn_mfma_f32_16x16x32_bf16(fh[r],  fl4[c], accG[r][c], 0, 0, 0);
                accG[r][c] = __builtin_amdgcn_mfma_f32_16x16x32_bf16(fl4[r], fh[c],  accG[r][c], 0, 0, 0);
            }
            accS[r] = __builtin_amdgcn_mfma_f32_16x16x32_bf16(fh[r],  ones, accS[r], 0, 0, 0);
            accS[r] = __builtin_amdgcn_mfma_f32_16x16x32_bf16(fl4[r], ones, accS[r], 0, 0, 0);
        }
        __syncthreads();   // drains next-chunk stage; protects buffer reuse
    }

#pragma unroll
    for (int r = 0; r < 3; ++r) {
#pragma unroll
        for (int c = 0; c < 3; ++c) {
#pragma unroll
            for (int i = 0; i < 4; ++i) {
                int m = r * 16 + quad * 4 + i;
                int n = c * 16 + row16;
                if (m < 34 && n < 34) sm.b.Gpart[w][m][n] = accG[r][c][i];
            }
        }
        if (row16 == 0) {
#pragma unroll
            for (int i = 0; i < 4; ++i) {
                int m = r * 16 + quad * 4 + i;
                if (m < 34) sm.b.spart[w][m] = accS[r][i];
            }
        }
    }
    __syncthreads();
    float* gout = ws + (size_t)b * GS_STRIDE;
    for (int idx = tid; idx < 1156; idx += 256) {
        int m = idx / 34, n = idx - m * 34;
        atomicAdd(&gout[idx], sm.b.Gpart[0][m][n] + sm.b.Gpart[1][m][n] +
                              sm.b.Gpart[2][m][n] + sm.b.Gpart[3][m][n]);
    }
    if (tid < 34)
        atomicAdd(&gout[1156 + tid], sm.b.spart[0][tid] + sm.b.spart[1][tid] +
                                     sm.b.spart[2][tid] + sm.b.spart[3][tid]);
}

// ---------------------------------------------------------------------------
// K2: per-batch affine chain, wave-synchronous, ALL MATMULS ON MFMA.
// The serial VALU chain (~16K FMA/wave) was the 90 us wall (1 wave/SIMD, no
// TLP). Each 36x36 mm is now 9 tiles of 16x16x32 bf16 MFMA with hi/lo split
// (same numerics as K1/K3): K=0..31 via full frags, e=32..35 via a second
// MFMA whose frags are nonzero only in quad 0. Matrices live in LDS as
// [36][44] f32 (stride 44: 16B-aligned rows, 2-way bank alias = free).
// Garbage rows/cols (34..35 clamps, stale W-scratch cols>=34) always multiply
// a structural zero: Sc rows 34/35 are zeroed every layer => At cols 34/35
// are zero => W-scratch cols >=34 are annihilated.
// ---------------------------------------------------------------------------
#define RST 44
#define RSZ (36 * RST)        // 1584 f32 per region
#define R_G0 0
#define R_At (1 * RSZ)
#define R_Aq (2 * RSZ)
#define R_Ak (3 * RSZ)
#define R_Av (4 * RSZ)        // AvT
#define R_S1 (5 * RSZ)
#define R_Sc (6 * RSZ)
#define R_Wx (7 * RSZ)
#define SMF  (8 * RSZ)        // 12672 f32 = 50688 B

__device__ __forceinline__ void ldfrag8(const float* p, v8s* hi, v8s* lo) {
    float f[8];
    *(float4*)&f[0] = *(const float4*)p;
    *(float4*)&f[4] = *(const float4*)(p + 4);
    split8(f, hi, lo);
}

// e = 32..35 frag: only quad 0 carries data (k elements 0..3), rest zero
__device__ __forceinline__ void ldfrag4(const float* p, int quad, v8s* hi, v8s* lo) {
    union { unsigned int u[4]; v8s s; } H, L;
#pragma unroll
    for (int i = 0; i < 4; ++i) { H.u[i] = 0; L.u[i] = 0; }
    if (quad == 0) {
        float4 f = *(const float4*)p;
        unsigned int h0 = cvtpk_bf16(f.x, f.y);
        unsigned int h1 = cvtpk_bf16(f.z, f.w);
        float r0 = f.x - __uint_as_float(h0 << 16);
        float r1 = f.y - __uint_as_float(h0 & 0xFFFF0000u);
        float r2 = f.z - __uint_as_float(h1 << 16);
        float r3 = f.w - __uint_as_float(h1 & 0xFFFF0000u);
        H.u[0] = h0; H.u[1] = h1;
        L.u[0] = cvtpk_bf16(r0, r1);
        L.u[1] = cvtpk_bf16(r2, r3);
    }
    *hi = H.s;
    *lo = L.s;
}

// D[i][j] = sum_{e<36} L[i][e] * R[j][e]  (both LDS, stride RST, rows>=36
// clamp to 35). transD=1 writes D[j][i] (b128 per tile). hi/lo split: 3
// cross-products per K-chunk.
__device__ __forceinline__ void mfma_mm(float* __restrict__ SMD, int Lo, int Ro,
                                        int Do, int l, bool transD) {
    const int lc = l & 15, quad = l >> 4;
    v8s Bh0[3], Bl0[3], Bh1[3], Bl1[3];
#pragma unroll
    for (int tn = 0; tn < 3; ++tn) {
        int r = tn * 16 + lc; r = r < 36 ? r : 35;
        const float* p = SMD + Ro + r * RST;
        ldfrag8(p + quad * 8, &Bh0[tn], &Bl0[tn]);
        ldfrag4(p + 32, quad, &Bh1[tn], &Bl1[tn]);
    }
#pragma unroll
    for (int tm = 0; tm < 3; ++tm) {
        int r = tm * 16 + lc; r = r < 36 ? r : 35;
        const float* p = SMD + Lo + r * RST;
        v8s Ah0, Al0, Ah1, Al1;
        ldfrag8(p + quad * 8, &Ah0, &Al0);
        ldfrag4(p + 32, quad, &Ah1, &Al1);
#pragma unroll
        for (int tn = 0; tn < 3; ++tn) {
            v4f acc = {0.f, 0.f, 0.f, 0.f};
            acc = __builtin_amdgcn_mfma_f32_16x16x32_bf16(Ah0, Bh0[tn], acc, 0, 0, 0);
            acc = __builtin_amdgcn_mfma_f32_16x16x32_bf16(Ah0, Bl0[tn], acc, 0, 0, 0);
            acc = __builtin_amdgcn_mfma_f32_16x16x32_bf16(Al0, Bh0[tn], acc, 0, 0, 0);
            acc = __builtin_amdgcn_mfma_f32_16x16x32_bf16(Ah1, Bh1[tn], acc, 0, 0, 0);
            acc = __builtin_amdgcn_mfma_f32_16x16x32_bf16(Ah1, Bl1[tn], acc, 0, 0, 0);
            acc = __builtin_amdgcn_mfma_f32_16x16x32_bf16(Al1, Bh1[tn], acc, 0, 0, 0);
            if (!transD) {
                int gcol = tn * 16 + lc;
                if (gcol < 36) {
#pragma unroll
                    for (int i = 0; i < 4; ++i) {
                        int grow = tm * 16 + quad * 4 + i;
                        if (grow < 36) SMD[Do + grow * RST + gcol] = acc[i];
                    }
                }
            } else {
                int trow = tn * 16 + lc;
                int tcol = tm * 16 + quad * 4;
                if (trow < 36 && tcol < 36)
                    *(v4f*)&SMD[Do + trow * RST + tcol] = acc;
            }
        }
    }
}

__global__ __launch_bounds__(64) void k_chain(
    const float* __restrict__ wq, const float* __restrict__ bq,
    const float* __restrict__ wk, const float* __restrict__ bk,
    const float* __restrict__ wv, const float* __restrict__ bv,
    const float* __restrict__ w1, const float* __restrict__ b1,
    const float* __restrict__ gamma, const float* __restrict__ beta,
    const float* __restrict__ mean, const float* __restrict__ var,
    float* __restrict__ ws) {
    __shared__ __align__(16) float SMD[SMF];
    const int l = threadIdx.x;
    const int b = blockIdx.x;
    const float* gsb = ws + (size_t)b * GS_STRIDE;

    // zero all LDS (pads must be 0 and stay 0)
    {
        const float4 z = make_float4(0.f, 0.f, 0.f, 0.f);
        for (int i = l * 4; i < SMF; i += 256) *(float4*)(SMD + i) = z;
    }
    __syncthreads();
    // augmented G0 + layer-0 shortcut (A=I, a=0): Aq=wq0(+bq col34),
    // Ak=wk0(+bk col34), AvT=wv0^T(+bv row34)
    for (int idx = l; idx < 1156; idx += 64) {
        int m = idx / 34, n = idx - m * 34;
        SMD[R_G0 + m * RST + n] = gsb[idx];
        SMD[R_Aq + m * RST + n] = wq[idx];
        SMD[R_Ak + m * RST + n] = wk[idx];
        SMD[R_Av + n * RST + m] = wv[idx];
    }
    if (l < 34) {
        float s = gsb[1156 + l];
        SMD[R_G0 + 34 * RST + l] = s;
        SMD[R_G0 + l * RST + 34] = s;
        SMD[R_Aq + l * RST + 34] = bq[l];
        SMD[R_Ak + l * RST + 34] = bk[l];
        SMD[R_Av + 34 * RST + l] = bv[l];
    }
    if (l == 0) SMD[R_G0 + 34 * RST + 34] = 2048.0f;
    __syncthreads();

    for (int lyr = 0; lyr < 3; ++lyr) {
        if (lyr > 0) {
            const float* wql = wq + lyr * 1156;
            const float* wkl = wk + lyr * 1156;
            const float* wvl = wv + lyr * 1156;
            // stage weights into dead scratch regions (cols>=34 of scratch may
            // be stale/nonzero: annihilated by At cols 34/35 == 0)
            for (int idx = l; idx < 1156; idx += 64) {
                int m = idx / 34, n = idx - m * 34;
                SMD[R_S1 + m * RST + n] = wql[idx];
                SMD[R_Sc + m * RST + n] = wkl[idx];
                SMD[R_Wx + m * RST + n] = wvl[idx];
            }
            __syncthreads();
            // stage1: Aq = Wq*A^, Ak = Wk*A^, AvT = (Wv*A^)^T
            mfma_mm(SMD, R_S1, R_At, R_Aq, l, false);
            mfma_mm(SMD, R_Sc, R_At, R_Ak, l, false);
            mfma_mm(SMD, R_Wx, R_At, R_Av, l, true);
            __syncthreads();
            if (l < 34) {     // biases into the offset slots
                SMD[R_Aq + l * RST + 34] += bq[lyr * 34 + l];
                SMD[R_Ak + l * RST + 34] += bk[lyr * 34 + l];
                SMD[R_Av + 34 * RST + l] += bv[lyr * 34 + l];
            }
            __syncthreads();
        }
        // stage2: S1 = Aq^ * G0^  (G0^ symmetric, augmented)
        mfma_mm(SMD, R_Aq, R_G0, R_S1, l, false);
        __syncthreads();
        // stage3: Sc = S1 * Ak^T  (exact augmented scores via e=34 term)
        mfma_mm(SMD, R_S1, R_Ak, R_Sc, l, false);
        __syncthreads();
        // stage4: row softmax (rows<34); lanes 36..53 zero Sc rows 34/35
        if (l < 34) {
            float f[36];
#pragma unroll
            for (int e0 = 0; e0 < 36; e0 += 4)
                *(float4*)&f[e0] = *(const float4*)&SMD[R_Sc + l * RST + e0];
            const float scale = 0.022097086912079608f;   // 1/sqrt(2048)
            float mx = -1e30f;
#pragma unroll
            for (int d = 0; d < 34; ++d) { f[d] *= scale; mx = fmaxf(mx, f[d]); }
            float sum = 0.f;
#pragma unroll
            for (int d = 0; d < 34; ++d) { float e = __expf(f[d] - mx); f[d] = e; sum += e; }
            float rs = 1.0f / sum;
#pragma unroll
            for (int d = 0; d < 34; ++d) f[d] *= rs;
            f[34] = 0.f; f[35] = 0.f;
#pragma unroll
            for (int e0 = 0; e0 < 36; e0 += 4)
                *(float4*)&SMD[R_Sc + l * RST + e0] = *(const float4*)&f[e0];
        } else if (l >= 36 && l < 54) {
            int u = l - 36;                       // zero Sc rows 34,35 cols 0..35
            int row = 34 + u / 9, c4 = (u - (u / 9) * 9) * 4;
            *(float4*)&SMD[R_Sc + row * RST + c4] = make_float4(0.f, 0.f, 0.f, 0.f);
        }
        __syncthreads();
        // stage5: At' = AvT^ * attn^T; row 34 propagates the offset
        mfma_mm(SMD, R_Av, R_Sc, R_At, l, false);
        __syncthreads();
    }

    // head: stage w1 into Sc (its cols>=34 / rows>=34 are clean zeros)
    for (int idx = l; idx < 544; idx += 64) {
        int m = idx / 34, n = idx - m * 34;
        SMD[R_Sc + m * RST + n] = w1[idx];
    }
    __syncthreads();
    mfma_mm(SMD, R_Sc, R_At, R_S1, l, false);   // S1[o][j], col34 = W1*a
    __syncthreads();
    // emit compact Wy': bf16 hi/lo planes (c<32), f32 cols 32/33, cy
    float* wb = ws + RB_OFF + (size_t)b * RB_STRIDE;
    if (l < 16) {
        float iv = gamma[l] * rsqrtf(var[l] + 1e-5f);
        float cyraw = SMD[R_S1 + l * RST + 34] + b1[l];
        wb[512 + l] = (cyraw - mean[l]) * iv + beta[l];   // cy'
        wb[528 + l] = SMD[R_S1 + l * RST + 32] * iv;      // wy32
        wb[544 + l] = SMD[R_S1 + l * RST + 33] * iv;      // wy33
    }
    unsigned short* wp = (unsigned short*)wb;
    for (int i = l; i < 512; i += 64) {
        int o = i >> 5, c = i & 31;
        float iv = gamma[o] * rsqrtf(var[o] + 1e-5f);
        float vv = SMD[R_S1 + o * RST + c] * iv;
        unsigned short hb = f2bf(vv);
        wp[i] = hb;
        wp[512 + i] = f2bf(vv - bf2f(hb));
    }
}

// ---------------------------------------------------------------------------
// K3: out = w2 * leaky(Wy' h0 + cy') + b2.
// ---------------------------------------------------------------------------
__global__ __launch_bounds__(256, 4) void k_out(const float* __restrict__ x,
                                                const float* __restrict__ w2,
                                                const float* __restrict__ b2,
                                                const float* __restrict__ ws,
                                                float* __restrict__ out) {
    __shared__ __align__(16) float raw[2][4352];

    const int tid  = threadIdx.x;
    const int b    = blockIdx.x >> 3;
    const int seg  = (blockIdx.x & 7) * 256;
    const int l    = tid & 63;
    const int w    = tid >> 6;
    const int quad = l >> 4;
    const int col  = l & 15;

    const float* wb = ws + RB_OFF + (size_t)b * RB_STRIDE;
    const unsigned short* wp = (const unsigned short*)wb;
    v8s aH = *(const v8s*)&wp[col * 32 + quad * 8];
    v8s aL = *(const v8s*)&wp[512 + col * 32 + quad * 8];
    float cyr[4], w2r[3][4], wy32r[4], wy33r[4];
#pragma unroll
    for (int i = 0; i < 4; ++i) {
        int o = quad * 4 + i;
        cyr[i]   = wb[512 + o];
        wy32r[i] = wb[528 + o];
        wy33r[i] = wb[544 + o];
#pragma unroll
        for (int p = 0; p < 3; ++p) w2r[p][i] = w2[p * 16 + o];
    }
    float b2r[3] = {b2[0], b2[1], b2[2]};
    const float* xb = x + (size_t)b * XB;

    int offq[8];
#pragma unroll
    for (int e = 0; e < 8; ++e) {
        int c = quad * 8 + e;
        offq[e] = (c >= 17) ? (2159 + c) : c;   // = co*2176 + v
    }

    stage_chunk(xb, seg, raw[0], w, l);
    __syncthreads();

    for (int ch = 0; ch < 2; ++ch) {
        if (ch == 0) stage_chunk(xb, seg + 128, raw[1], w, l);
        for (int tt = w; tt < 8; tt += 4) {
            const int tl = tt * 16 + col;
            const float* rbt = raw[ch] + tl * 17;
            float f[8];
#pragma unroll
            for (int e = 0; e < 8; ++e) f[e] = rbt[offq[e]];
            v8s bH, bL;
            split8(f, &bH, &bL);
            v4f acc = {0.f, 0.f, 0.f, 0.f};
            acc = __builtin_amdgcn_mfma_f32_16x16x32_bf16(aH, bH, acc, 0, 0, 0);
            acc = __builtin_amdgcn_mfma_f32_16x16x32_bf16(aH, bL, acc, 0, 0, 0);
            acc = __builtin_amdgcn_mfma_f32_16x16x32_bf16(aL, bH, acc, 0, 0, 0);
            float h32 = rbt[2191];   // c=32 (co1, v15)
            float h33 = rbt[2192];   // c=33 (co1, v16)
            float op[3] = {0, 0, 0};
#pragma unroll
            for (int i = 0; i < 4; ++i) {
                float y = acc[i] + cyr[i] + wy32r[i] * h32 + wy33r[i] * h33;
                float z = (y > 0.f) ? y : 0.01f * y;
#pragma unroll
                for (int p = 0; p < 3; ++p) op[p] += w2r[p][i] * z;
            }
#pragma unroll
            for (int p = 0; p < 3; ++p) {
                op[p] += __shfl_xor(op[p], 16);
                op[p] += __shfl_xor(op[p], 32);
            }
            if (l < 16) {
                int tg = seg + ch * 128 + tt * 16 + l;
#pragma unroll
                for (int p = 0; p < 3; ++p)
                    out[((size_t)b * 3 + p) * 2048 + tg] = op[p] + b2r[p];
            }
        }
        __syncthreads();   // drains chunk-1 stage; protects buffer before exit
    }
}

extern "C" void kernel_launch(void* const* d_in, const int* in_sizes, int n_in,
                              void* d_out, int out_size, void* d_ws, size_t ws_size,
                              hipStream_t stream) {
    const float* x     = (const float*)d_in[0];
    const float* wq    = (const float*)d_in[1];
    const float* bq    = (const float*)d_in[2];
    const float* wk    = (const float*)d_in[3];
    const float* bk    = (const float*)d_in[4];
    const float* wv    = (const float*)d_in[5];
    const float* bv    = (const float*)d_in[6];
    const float* w1    = (const float*)d_in[7];
    const float* b1    = (const float*)d_in[8];
    const float* gamma = (const float*)d_in[9];
    const float* beta  = (const float*)d_in[10];
    const float* mean  = (const float*)d_in[11];
    const float* var   = (const float*)d_in[12];
    const float* w2    = (const float*)d_in[13];
    const float* b2    = (const float*)d_in[14];
    float* ws  = (float*)d_ws;
    float* out = (float*)d_out;

    hipMemsetAsync(d_ws, 0, (size_t)NB * GS_STRIDE * sizeof(float), stream);
    k_gram<<<dim3(2048), dim3(256), 0, stream>>>(x, ws);
    k_chain<<<dim3(512), dim3(64), 0, stream>>>(wq, bq, wk, bk, wv, bv,
                                                w1, b1, gamma, beta, mean, var, ws);
    k_out<<<dim3(4096), dim3(256), 0, stream>>>(x, w2, b2, ws, out);
}

// Round 6
// 277.190 us; speedup vs baseline: 2.1873x; 1.1421x over previous
//
#include <hip/hip_runtime.h>

// Problem constants
#define CV   34          // C*V channels
#define TTOT 2048        // T
#define NB   512         // batches
#define XB   69632       // x per-batch stride (2*2048*17)
#define XC   34816       // x per-co stride (2048*17)

// Workspace layout (floats): region B only (no Gram region needed anymore)
// per batch: 1024 ushort (hi/lo bf16 planes, 16x32) = 512 f,
// then cy[16], wy32[16], wy33[16] f32 -> 560 f, padded to 576
#define RB_STRIDE 576

typedef __attribute__((ext_vector_type(8))) short v8s;   // 8 x bf16 (MFMA A/B frag)
typedef __attribute__((ext_vector_type(4))) float v4f;   // 4 x f32 (MFMA C/D frag)

__device__ __forceinline__ unsigned short f2bf(float f) {
    unsigned int u = __float_as_uint(f);
    u = u + 0x7FFFu + ((u >> 16) & 1u);   // round-to-nearest-even
    return (unsigned short)(u >> 16);
}
__device__ __forceinline__ float bf2f(unsigned short s) {
    return __uint_as_float(((unsigned int)s) << 16);
}

__device__ __forceinline__ unsigned int cvtpk_bf16(float a, float b) {
    unsigned int r;   // r.lo16 = bf16(a), r.hi16 = bf16(b), RNE
    asm("v_cvt_pk_bf16_f32 %0, %1, %2" : "=v"(r) : "v"(a), "v"(b));
    return r;
}

// split 8 f32 -> packed hi/lo bf16 MFMA fragments (RNE; residual exact in f32)
__device__ __forceinline__ void split8(const float (&f)[8], v8s* hi, v8s* lo) {
    union { unsigned int u[4]; v8s s; } H, L;
#pragma unroll
    for (int p = 0; p < 4; ++p) {
        float a = f[2 * p], b = f[2 * p + 1];
        unsigned int h = cvtpk_bf16(a, b);
        float ra = a - __uint_as_float(h << 16);
        float rb = b - __uint_as_float(h & 0xFFFF0000u);
        L.u[p] = cvtpk_bf16(ra, rb);
        H.u[p] = h;
    }
    *hi = H.s;
    *lo = L.s;
}

// async-stage one 128-t chunk (2 co x 2176 floats, verbatim global order) to LDS.
// 17 x global_load_lds(16B); wave w issues instrs {w, w+4, ...}.
__device__ __forceinline__ void stage_chunk(const float* __restrict__ xb, int t0,
                                            float* rawbuf, int w, int lane) {
#pragma unroll
    for (int i = 0; i < 5; ++i) {
        int idx = i * 4 + w;
        if (idx < 17) {
            int fl = idx * 256 + lane * 4;
            int co = (fl >= 2176) ? 1 : 0;
            const float* g = xb + t0 * 17 + fl + co * 32640;   // 32640 = XC - 2176
            __builtin_amdgcn_global_load_lds(
                (const __attribute__((address_space(1))) void*)g,
                (__attribute__((address_space(3))) void*)(rawbuf + idx * 256),
                16, 0, 0);
        }
    }
}

// ---------------------------------------------------------------------------
// K_FUSED: per-batch Gram (MFMA over 16 chunks) + affine chain (MFMA, 3-wave
// tile split), one block = one batch, 256 threads (4 waves).
// Gram: wave w owns k-slice w of each chunk, accumulates G/s0 in registers;
// partials reduced in LDS (no atomics, no ws round-trip, no memset).
// Chain: round-5 augmented-matrix MFMA chain; each 36x36 mm's 9 tiles are
// split tm->wave (waves 0..2), barriers between stages.
// LDS: 8 regions [36][44] f32 = 50,688 B; gram staging (2x17,408 B) aliases
// regions R_Aq.. during the gram phase (dead then, rebuilt after).
// ---------------------------------------------------------------------------
#define RST 44
#define RSZ (36 * RST)        // 1584 f32 per region
#define R_G0 0
#define R_At (1 * RSZ)
#define R_Aq (2 * RSZ)
#define R_Ak (3 * RSZ)
#define R_Av (4 * RSZ)        // AvT
#define R_S1 (5 * RSZ)
#define R_Sc (6 * RSZ)
#define R_Wx (7 * RSZ)
#define SMF  (8 * RSZ)        // 12672 f32 = 50688 B

__device__ __forceinline__ void ldfrag8(const float* p, v8s* hi, v8s* lo) {
    float f[8];
    *(float4*)&f[0] = *(const float4*)p;
    *(float4*)&f[4] = *(const float4*)(p + 4);
    split8(f, hi, lo);
}

// e = 32..35 frag: only quad 0 carries data (k elements 0..3), rest zero
__device__ __forceinline__ void ldfrag4(const float* p, int quad, v8s* hi, v8s* lo) {
    union { unsigned int u[4]; v8s s; } H, L;
#pragma unroll
    for (int i = 0; i < 4; ++i) { H.u[i] = 0; L.u[i] = 0; }
    if (quad == 0) {
        float4 f = *(const float4*)p;
        unsigned int h0 = cvtpk_bf16(f.x, f.y);
        unsigned int h1 = cvtpk_bf16(f.z, f.w);
        float r0 = f.x - __uint_as_float(h0 << 16);
        float r1 = f.y - __uint_as_float(h0 & 0xFFFF0000u);
        float r2 = f.z - __uint_as_float(h1 << 16);
        float r3 = f.w - __uint_as_float(h1 & 0xFFFF0000u);
        H.u[0] = h0; H.u[1] = h1;
        L.u[0] = cvtpk_bf16(r0, r1);
        L.u[1] = cvtpk_bf16(r2, r3);
    }
    *hi = H.s;
    *lo = L.s;
}

// D[i][j] = sum_{e<36} L[i][e]*R[j][e], tiles split tm -> wave (waves 0..2).
// transD=1 writes D[j][i]. Garbage clamp rows (34/35 dup) land in discarded
// output rows/cols; state invariants (rows/cols 34/35 structure) as round 5.
__device__ __forceinline__ void mfma_mm3(float* __restrict__ SMD, int Lo, int Ro,
                                         int Do, int wave, int lane, bool transD) {
    if (wave >= 3) return;
    const int lc = lane & 15, quad = lane >> 4;
    const int tm = wave;
    int ra = tm * 16 + lc; ra = ra < 36 ? ra : 35;
    const float* pa = SMD + Lo + ra * RST;
    v8s Ah0, Al0, Ah1, Al1;
    ldfrag8(pa + quad * 8, &Ah0, &Al0);
    ldfrag4(pa + 32, quad, &Ah1, &Al1);
#pragma unroll
    for (int tn = 0; tn < 3; ++tn) {
        int rb = tn * 16 + lc; rb = rb < 36 ? rb : 35;
        const float* pb = SMD + Ro + rb * RST;
        v8s Bh0, Bl0, Bh1, Bl1;
        ldfrag8(pb + quad * 8, &Bh0, &Bl0);
        ldfrag4(pb + 32, quad, &Bh1, &Bl1);
        v4f acc = {0.f, 0.f, 0.f, 0.f};
        acc = __builtin_amdgcn_mfma_f32_16x16x32_bf16(Ah0, Bh0, acc, 0, 0, 0);
        acc = __builtin_amdgcn_mfma_f32_16x16x32_bf16(Ah0, Bl0, acc, 0, 0, 0);
        acc = __builtin_amdgcn_mfma_f32_16x16x32_bf16(Al0, Bh0, acc, 0, 0, 0);
        acc = __builtin_amdgcn_mfma_f32_16x16x32_bf16(Ah1, Bh1, acc, 0, 0, 0);
        acc = __builtin_amdgcn_mfma_f32_16x16x32_bf16(Ah1, Bl1, acc, 0, 0, 0);
        acc = __builtin_amdgcn_mfma_f32_16x16x32_bf16(Al1, Bh1, acc, 0, 0, 0);
        if (!transD) {
            int gcol = tn * 16 + lc;
            if (gcol < 36) {
#pragma unroll
                for (int i = 0; i < 4; ++i) {
                    int grow = tm * 16 + quad * 4 + i;
                    if (grow < 36) SMD[Do + grow * RST + gcol] = acc[i];
                }
            }
        } else {
            int trow = tn * 16 + lc;
            int tcol = tm * 16 + quad * 4;
            if (trow < 36 && tcol < 36)
                *(v4f*)&SMD[Do + trow * RST + tcol] = acc;
        }
    }
}

__global__ __launch_bounds__(256) void k_fused(
    const float* __restrict__ x,
    const float* __restrict__ wq, const float* __restrict__ bq,
    const float* __restrict__ wk, const float* __restrict__ bk,
    const float* __restrict__ wv, const float* __restrict__ bv,
    const float* __restrict__ w1, const float* __restrict__ b1,
    const float* __restrict__ gamma, const float* __restrict__ beta,
    const float* __restrict__ mean, const float* __restrict__ var,
    float* __restrict__ ws) {
    __shared__ __align__(16) float SMD[SMF];
    const int tid  = threadIdx.x;
    const int wave = tid >> 6;
    const int l    = tid & 63;
    const int b    = blockIdx.x;
    const int row16 = l & 15;
    const int quad  = l >> 4;
    const float* xb = x + (size_t)b * XB;

    // ---------------- Gram phase (staging aliases R_Aq..): 16 chunks --------
    float* raw0 = SMD + R_Aq;            // 4352 f
    float* raw1 = SMD + R_Aq + 4352;     // 4352 f

    int offc[3];
#pragma unroll
    for (int r = 0; r < 3; ++r) {
        int c = r * 16 + row16;
        if (c > 33) c = 33;
        offc[r] = (c >= 17) ? (2159 + c) : c;   // = co*2176 + v
    }
    const int koff = wave * 32 + quad * 8;      // t offset within 128-t chunk

    v4f accG[3][3];
    v4f accS[3];
    {
        v4f vz = {0.f, 0.f, 0.f, 0.f};
#pragma unroll
        for (int r = 0; r < 3; ++r) {
            accS[r] = vz;
#pragma unroll
            for (int c = 0; c < 3; ++c) accG[r][c] = vz;
        }
    }
    v8s ones;
#pragma unroll
    for (int i = 0; i < 8; ++i) ones[i] = (short)0x3F80;   // bf16 1.0

    stage_chunk(xb, 0, raw0, wave, l);
    __syncthreads();                            // chunk 0 ready

    for (int ch = 0; ch < 16; ++ch) {
        float* cur = (ch & 1) ? raw1 : raw0;
        float* nxt = (ch & 1) ? raw0 : raw1;
        if (ch < 15) stage_chunk(xb, (ch + 1) * 128, nxt, wave, l);

        const float* rb = cur + koff * 17;
        v8s fh[3], fl4[3];
#pragma unroll
        for (int r = 0; r < 3; ++r) {
            const float* p = rb + offc[r];
            float f[8];
#pragma unroll
            for (int e = 0; e < 8; ++e) f[e] = p[e * 17];
            split8(f, &fh[r], &fl4[r]);
        }
#pragma unroll
        for (int r = 0; r < 3; ++r) {
#pragma unroll
            for (int c = 0; c < 3; ++c) {
                accG[r][c] = __builtin_amdgcn_mfma_f32_16x16x32_bf16(fh[r],  fh[c],  accG[r][c], 0, 0, 0);
                accG[r][c] = __builtin_amdgcn_mfma_f32_16x16x32_bf16(fh[r],  fl4[c], accG[r][c], 0, 0, 0);
                accG[r][c] = __builtin_amdgcn_mfma_f32_16x16x32_bf16(fl4[r], fh[c],  accG[r][c], 0, 0, 0);
            }
            accS[r] = __builtin_amdgcn_mfma_f32_16x16x32_bf16(fh[r],  ones, accS[r], 0, 0, 0);
            accS[r] = __builtin_amdgcn_mfma_f32_16x16x32_bf16(fl4[r], ones, accS[r], 0, 0, 0);
        }
        __syncthreads();   // next-chunk stage drained; buffer safe to reuse
    }

    // write wave partials into regions R_At..R_Av ([34][.] at stride RST;
    // s0 partial in row 34). raw is dead (barrier above).
    {
        float* gp = SMD + R_At + wave * RSZ;
#pragma unroll
        for (int r = 0; r < 3; ++r) {
#pragma unroll
            for (int c = 0; c < 3; ++c) {
#pragma unroll
                for (int i = 0; i < 4; ++i) {
                    int m = r * 16 + quad * 4 + i;
                    int n = c * 16 + row16;
                    if (m < 34 && n < 34) gp[m * RST + n] = accG[r][c][i];
                }
            }
            if (row16 == 0) {
#pragma unroll
                for (int i = 0; i < 4; ++i) {
                    int m = r * 16 + quad * 4 + i;
                    if (m < 34) gp[34 * RST + m] = accS[r][i];
                }
            }
        }
    }
    __syncthreads();
    // reduce partials into registers (<=5 G entries/thread + s0 for tid<34)
    float gred[5];
    int   gm[5], gn[5];
#pragma unroll
    for (int k = 0; k < 5; ++k) {
        int idx = tid + k * 256;
        if (idx < 1156) {
            int m = idx / 34, n = idx - m * 34;
            gm[k] = m; gn[k] = n;
            gred[k] = SMD[R_At + m * RST + n] + SMD[R_Aq + m * RST + n] +
                      SMD[R_Ak + m * RST + n] + SMD[R_Av + m * RST + n];
        } else { gm[k] = -1; gn[k] = 0; gred[k] = 0.f; }
    }
    float s0red = 0.f;
    if (tid < 34)
        s0red = SMD[R_At + 34 * RST + tid] + SMD[R_Aq + 34 * RST + tid] +
                SMD[R_Ak + 34 * RST + tid] + SMD[R_Av + 34 * RST + tid];
    __syncthreads();
    // zero ALL regions (pads must be 0 and stay 0 per chain invariants)
    {
        const float4 z = make_float4(0.f, 0.f, 0.f, 0.f);
        for (int i = tid * 4; i < SMF; i += 1024) *(float4*)(SMD + i) = z;
    }
    __syncthreads();
    // build augmented G0 + layer-0 shortcut (A=I, a=0)
#pragma unroll
    for (int k = 0; k < 5; ++k)
        if (gm[k] >= 0) SMD[R_G0 + gm[k] * RST + gn[k]] = gred[k];
    for (int idx = tid; idx < 1156; idx += 256) {
        int m = idx / 34, n = idx - m * 34;
        SMD[R_Aq + m * RST + n] = wq[idx];
        SMD[R_Ak + m * RST + n] = wk[idx];
        SMD[R_Av + n * RST + m] = wv[idx];
    }
    if (tid < 34) {
        SMD[R_G0 + 34 * RST + tid] = s0red;
        SMD[R_G0 + tid * RST + 34] = s0red;
        SMD[R_Aq + tid * RST + 34] = bq[tid];
        SMD[R_Ak + tid * RST + 34] = bk[tid];
        SMD[R_Av + 34 * RST + tid] = bv[tid];
    }
    if (tid == 0) SMD[R_G0 + 34 * RST + 34] = 2048.0f;
    __syncthreads();

    // ---------------- Chain phase (3-wave tile-split MFMA mms) --------------
    for (int lyr = 0; lyr < 3; ++lyr) {
        if (lyr > 0) {
            const float* wql = wq + lyr * 1156;
            const float* wkl = wk + lyr * 1156;
            const float* wvl = wv + lyr * 1156;
            for (int idx = tid; idx < 1156; idx += 256) {
                int m = idx / 34, n = idx - m * 34;
                SMD[R_S1 + m * RST + n] = wql[idx];
                SMD[R_Sc + m * RST + n] = wkl[idx];
                SMD[R_Wx + m * RST + n] = wvl[idx];
            }
            __syncthreads();
            // stage1: Aq = Wq*A^, Ak = Wk*A^, AvT = (Wv*A^)^T (independent mms)
            mfma_mm3(SMD, R_S1, R_At, R_Aq, wave, l, false);
            mfma_mm3(SMD, R_Sc, R_At, R_Ak, wave, l, false);
            mfma_mm3(SMD, R_Wx, R_At, R_Av, wave, l, true);
            __syncthreads();
            if (tid < 34) {     // biases into the offset slots
                SMD[R_Aq + tid * RST + 34] += bq[lyr * 34 + tid];
                SMD[R_Ak + tid * RST + 34] += bk[lyr * 34 + tid];
                SMD[R_Av + 34 * RST + tid] += bv[lyr * 34 + tid];
            }
            __syncthreads();
        }
        // stage2: S1 = Aq^ * G0^  (augmented, symmetric G0)
        mfma_mm3(SMD, R_Aq, R_G0, R_S1, wave, l, false);
        __syncthreads();
        // stage3: Sc = S1 * Ak^T (exact augmented scores)
        mfma_mm3(SMD, R_S1, R_Ak, R_Sc, wave, l, false);
        __syncthreads();
        // stage4: row softmax (tid<34); tid 64..81 zero Sc rows 34/35
        if (tid < 34) {
            float f[36];
#pragma unroll
            for (int e0 = 0; e0 < 36; e0 += 4)
                *(float4*)&f[e0] = *(const float4*)&SMD[R_Sc + tid * RST + e0];
            const float scale = 0.022097086912079608f;   // 1/sqrt(2048)
            float mx = -1e30f;
#pragma unroll
            for (int d = 0; d < 34; ++d) { f[d] *= scale; mx = fmaxf(mx, f[d]); }
            float sum = 0.f;
#pragma unroll
            for (int d = 0; d < 34; ++d) { float e = __expf(f[d] - mx); f[d] = e; sum += e; }
            float rs = 1.0f / sum;
#pragma unroll
            for (int d = 0; d < 34; ++d) f[d] *= rs;
            f[34] = 0.f; f[35] = 0.f;
#pragma unroll
            for (int e0 = 0; e0 < 36; e0 += 4)
                *(float4*)&SMD[R_Sc + tid * RST + e0] = *(const float4*)&f[e0];
        } else if (tid >= 64 && tid < 82) {
            int u = tid - 64;                     // zero Sc rows 34,35 cols 0..35
            int row = 34 + u / 9, c4 = (u - (u / 9) * 9) * 4;
            *(float4*)&SMD[R_Sc + row * RST + c4] = make_float4(0.f, 0.f, 0.f, 0.f);
        }
        __syncthreads();
        // stage5: At' = AvT^ * attn^T; row 34 propagates the offset
        mfma_mm3(SMD, R_Av, R_Sc, R_At, wave, l, false);
        __syncthreads();
    }

    // head: stage w1 (rows 0..15) into Sc, mm -> S1; col34 = W1*a
    for (int idx = tid; idx < 544; idx += 256) {
        int m = idx / 34, n = idx - m * 34;
        SMD[R_Sc + m * RST + n] = w1[idx];
    }
    __syncthreads();
    mfma_mm3(SMD, R_Sc, R_At, R_S1, wave, l, false);
    __syncthreads();
    // emit compact Wy': bf16 hi/lo planes (c<32), f32 cols 32/33, cy
    float* wb = ws + (size_t)b * RB_STRIDE;
    if (tid < 16) {
        float iv = gamma[tid] * rsqrtf(var[tid] + 1e-5f);
        float cyraw = SMD[R_S1 + tid * RST + 34] + b1[tid];
        wb[512 + tid] = (cyraw - mean[tid]) * iv + beta[tid];   // cy'
        wb[528 + tid] = SMD[R_S1 + tid * RST + 32] * iv;        // wy32
        wb[544 + tid] = SMD[R_S1 + tid * RST + 33] * iv;        // wy33
    }
    unsigned short* wp = (unsigned short*)wb;
    for (int i = tid; i < 512; i += 256) {
        int o = i >> 5, c = i & 31;
        float iv = gamma[o] * rsqrtf(var[o] + 1e-5f);
        float vv = SMD[R_S1 + o * RST + c] * iv;
        unsigned short hb = f2bf(vv);
        wp[i] = hb;
        wp[512 + i] = f2bf(vv - bf2f(hb));
    }
}

// ---------------------------------------------------------------------------
// K3: out = w2 * leaky(Wy' h0 + cy') + b2.
// ---------------------------------------------------------------------------
__global__ __launch_bounds__(256, 4) void k_out(const float* __restrict__ x,
                                                const float* __restrict__ w2,
                                                const float* __restrict__ b2,
                                                const float* __restrict__ ws,
                                                float* __restrict__ out) {
    __shared__ __align__(16) float raw[2][4352];

    const int tid  = threadIdx.x;
    const int b    = blockIdx.x >> 3;
    const int seg  = (blockIdx.x & 7) * 256;
    const int l    = tid & 63;
    const int w    = tid >> 6;
    const int quad = l >> 4;
    const int col  = l & 15;

    const float* wb = ws + (size_t)b * RB_STRIDE;
    const unsigned short* wp = (const unsigned short*)wb;
    v8s aH = *(const v8s*)&wp[col * 32 + quad * 8];
    v8s aL = *(const v8s*)&wp[512 + col * 32 + quad * 8];
    float cyr[4], w2r[3][4], wy32r[4], wy33r[4];
#pragma unroll
    for (int i = 0; i < 4; ++i) {
        int o = quad * 4 + i;
        cyr[i]   = wb[512 + o];
        wy32r[i] = wb[528 + o];
        wy33r[i] = wb[544 + o];
#pragma unroll
        for (int p = 0; p < 3; ++p) w2r[p][i] = w2[p * 16 + o];
    }
    float b2r[3] = {b2[0], b2[1], b2[2]};
    const float* xb = x + (size_t)b * XB;

    int offq[8];
#pragma unroll
    for (int e = 0; e < 8; ++e) {
        int c = quad * 8 + e;
        offq[e] = (c >= 17) ? (2159 + c) : c;   // = co*2176 + v
    }

    stage_chunk(xb, seg, raw[0], w, l);
    __syncthreads();

    for (int ch = 0; ch < 2; ++ch) {
        if (ch == 0) stage_chunk(xb, seg + 128, raw[1], w, l);
        for (int tt = w; tt < 8; tt += 4) {
            const int tl = tt * 16 + col;
            const float* rbt = raw[ch] + tl * 17;
            float f[8];
#pragma unroll
            for (int e = 0; e < 8; ++e) f[e] = rbt[offq[e]];
            v8s bH, bL;
            split8(f, &bH, &bL);
            v4f acc = {0.f, 0.f, 0.f, 0.f};
            acc = __builtin_amdgcn_mfma_f32_16x16x32_bf16(aH, bH, acc, 0, 0, 0);
            acc = __builtin_amdgcn_mfma_f32_16x16x32_bf16(aH, bL, acc, 0, 0, 0);
            acc = __builtin_amdgcn_mfma_f32_16x16x32_bf16(aL, bH, acc, 0, 0, 0);
            float h32 = rbt[2191];   // c=32 (co1, v15)
            float h33 = rbt[2192];   // c=33 (co1, v16)
            float op[3] = {0, 0, 0};
#pragma unroll
            for (int i = 0; i < 4; ++i) {
                float y = acc[i] + cyr[i] + wy32r[i] * h32 + wy33r[i] * h33;
                float z = (y > 0.f) ? y : 0.01f * y;
#pragma unroll
                for (int p = 0; p < 3; ++p) op[p] += w2r[p][i] * z;
            }
#pragma unroll
            for (int p = 0; p < 3; ++p) {
                op[p] += __shfl_xor(op[p], 16);
                op[p] += __shfl_xor(op[p], 32);
            }
            if (l < 16) {
                int tg = seg + ch * 128 + tt * 16 + l;
#pragma unroll
                for (int p = 0; p < 3; ++p)
                    out[((size_t)b * 3 + p) * 2048 + tg] = op[p] + b2r[p];
            }
        }
        __syncthreads();   // drains chunk-1 stage; protects buffer before exit
    }
}

extern "C" void kernel_launch(void* const* d_in, const int* in_sizes, int n_in,
                              void* d_out, int out_size, void* d_ws, size_t ws_size,
                              hipStream_t stream) {
    const float* x     = (const float*)d_in[0];
    const float* wq    = (const float*)d_in[1];
    const float* bq    = (const float*)d_in[2];
    const float* wk    = (const float*)d_in[3];
    const float* bk    = (const float*)d_in[4];
    const float* wv    = (const float*)d_in[5];
    const float* bv    = (const float*)d_in[6];
    const float* w1    = (const float*)d_in[7];
    const float* b1    = (const float*)d_in[8];
    const float* gamma = (const float*)d_in[9];
    const float* beta  = (const float*)d_in[10];
    const float* mean  = (const float*)d_in[11];
    const float* var   = (const float*)d_in[12];
    const float* w2    = (const float*)d_in[13];
    const float* b2    = (const float*)d_in[14];
    float* ws  = (float*)d_ws;
    float* out = (float*)d_out;

    k_fused<<<dim3(512), dim3(256), 0, stream>>>(x, wq, bq, wk, bk, wv, bv,
                                                 w1, b1, gamma, beta, mean, var, ws);
    k_out<<<dim3(4096), dim3(256), 0, stream>>>(x, w2, b2, ws, out);
}